// Round 6
// baseline (522.966 us; speedup 1.0000x reference)
//
#include <hip/hip_runtime.h>
#include <stdint.h>

typedef unsigned short u16;
typedef __bf16 bf16x8 __attribute__((ext_vector_type(8)));
typedef float f32x4 __attribute__((ext_vector_type(4)));
typedef float f4v __attribute__((ext_vector_type(4)));

#define AS1 __attribute__((address_space(1)))
#define AS3 __attribute__((address_space(3)))

// async global->LDS, 16B per lane; LDS dest is wave-uniform base + lane*16
__device__ __forceinline__ void gload_lds16(u16* lds_wave_base, const u16* g) {
  __builtin_amdgcn_global_load_lds((AS1 void*)g, (AS3 void*)lds_wave_base, 16, 0, 0);
}

__device__ __forceinline__ u16 f2bf(float f) {  // RNE fp32->bf16
  unsigned int u = __float_as_uint(f);
  u += 0x7fffu + ((u >> 16) & 1u);
  return (u16)(u >> 16);
}
__device__ __forceinline__ float bf2f(u16 h) { return __uint_as_float(((unsigned)h) << 16); }

// non-temporal float4 store (write-once streams: y, Spart)
__device__ __forceinline__ void nt_store_f4(float* p, float a, float b, float c, float d) {
  f4v v;
  v[0] = a; v[1] = b; v[2] = c; v[3] = d;
  __builtin_nontemporal_store(v, (f4v*)p);
}

// ---------------- cast fp32 -> bf16, 8 elements/thread (weights) ----------------
__global__ void cast_f32_bf16(const float* __restrict__ in, u16* __restrict__ out, int n8) {
  int i = blockIdx.x * blockDim.x + threadIdx.x;
  if (i >= n8) return;
  const float4* p = (const float4*)in + (size_t)i * 2;
  float4 a = p[0], b = p[1];
  uint2 lo, hi;
  lo.x = (unsigned)f2bf(a.x) | ((unsigned)f2bf(a.y) << 16);
  lo.y = (unsigned)f2bf(a.z) | ((unsigned)f2bf(a.w) << 16);
  hi.x = (unsigned)f2bf(b.x) | ((unsigned)f2bf(b.y) << 16);
  hi.y = (unsigned)f2bf(b.z) | ((unsigned)f2bf(b.w) << 16);
  uint2* o = (uint2*)out + (size_t)i * 2;
  o[0] = lo;
  o[1] = hi;
}

// ---------------- cast half: x fp32 -> bf16 natural + column sums ----------------
// grid 1024 = 16bp x 64-token chunks. 64 lanes cover a full 512-ch row (2KB read,
// 1KB write, perfectly coalesced). Pure stream, no barrier in the hot loop.
__global__ __launch_bounds__(256) void cast_x(const float* __restrict__ x,
                                              u16* __restrict__ xbf,
                                              float* __restrict__ svec) {
  __shared__ float sred[4 * 512];  // 8 KB
  const int b = blockIdx.x;
  const int bp = b >> 6;
  const int n0 = (b & 63) * 64;
  const int t = threadIdx.x;
  const int e8 = (t & 63) * 8;
  const int r0 = t >> 6;  // 0..3
  const float* xb = x + ((size_t)(bp * 4096 + n0) * 512) + e8;
  u16* ob = xbf + ((size_t)(bp * 4096 + n0) * 512) + e8;
  float s0 = 0.f, s1 = 0.f, s2 = 0.f, s3 = 0.f, s4 = 0.f, s5 = 0.f, s6 = 0.f, s7 = 0.f;
#pragma unroll 2
  for (int pass = 0; pass < 16; ++pass) {
    const int r = pass * 4 + r0;
    const float* p = xb + (size_t)r * 512;
    float4 v0 = *(const float4*)p;
    float4 v1 = *(const float4*)(p + 4);
    uint2 lo, hi;
    lo.x = (unsigned)f2bf(v0.x) | ((unsigned)f2bf(v0.y) << 16);
    lo.y = (unsigned)f2bf(v0.z) | ((unsigned)f2bf(v0.w) << 16);
    hi.x = (unsigned)f2bf(v1.x) | ((unsigned)f2bf(v1.y) << 16);
    hi.y = (unsigned)f2bf(v1.z) | ((unsigned)f2bf(v1.w) << 16);
    uint2* o = (uint2*)(ob + (size_t)r * 512);
    o[0] = lo;
    o[1] = hi;
    s0 += v0.x; s1 += v0.y; s2 += v0.z; s3 += v0.w;
    s4 += v1.x; s5 += v1.y; s6 += v1.z; s7 += v1.w;
  }
  float* sp = &sred[r0 * 512 + e8];
  sp[0] = s0; sp[1] = s1; sp[2] = s2; sp[3] = s3;
  sp[4] = s4; sp[5] = s5; sp[6] = s6; sp[7] = s7;
  __syncthreads();
  // 512 channels / 256 threads = 2 each; sum the 4 row-groups, one atomic per ch
  {
    const int e = t * 2;
    float a0 = sred[e] + sred[512 + e] + sred[1024 + e] + sred[1536 + e];
    float a1 = sred[e + 1] + sred[512 + e + 1] + sred[1024 + e + 1] + sred[1536 + e + 1];
    float* sv = svec + (size_t)bp * 512 + e;
    atomicAdd(sv + 0, a0);
    atomicAdd(sv + 1, a1);
  }
}

// ---------------- transpose half: x_bf [bp][n][E] -> x_bfT [bp][E][n] ------------
// grid 4096 = 16bp x 64 tok-tiles(64) x 4 E-tiles(128). bf16-only traffic (134 MB).
// LDS: dword [e:128][npair:32] stride 36 dw, col = (np&16)|((np^((e>>2)&15))&15),
// dword packs tokens {2np,2np+1} at channel e (round-2 verified scheme).
// 18432 B LDS -> 8 blocks/CU; all 8 loads issued up front.
__global__ __launch_bounds__(256) void transpose_x(const u16* __restrict__ xbf,
                                                   u16* __restrict__ xbfT) {
  __shared__ __align__(16) unsigned sm[128 * 36];  // 18432 B
  const int b = blockIdx.x;
  const int bp = b >> 8;
  const int tt = (b >> 2) & 63;
  const int et = b & 3;
  const int t = threadIdx.x;
  const int n0 = tt * 64, e0 = et * 128;
  const int c4 = (t & 31) * 4;  // 4 channels; (e>>2)&15 == t&15
  const int pr = t >> 5;        // 0..7 token-pair row
  const int sw1 = t & 15;
  const u16* ib = xbf + ((size_t)(bp * 4096 + n0) * 512) + e0 + c4;
  // issue all 8 loads up front
  uint2 ta[4], tb[4];
#pragma unroll
  for (int jp = 0; jp < 4; ++jp) {
    const int n = (jp * 8 + pr) * 2;
    ta[jp] = *(const uint2*)(ib + (size_t)n * 512);
    tb[jp] = *(const uint2*)(ib + (size_t)(n + 1) * 512);
  }
#pragma unroll
  for (int jp = 0; jp < 4; ++jp) {
    const int npair = jp * 8 + pr;
    const uint2 a = ta[jp], v = tb[jp];
    const int col = (npair & 16) | ((npair ^ sw1) & 15);
    // dword k: lo16 = tok n ch c4+k, hi16 = tok n+1 ch c4+k
    sm[(c4 + 0) * 36 + col] = (a.x & 0xFFFFu) | (v.x << 16);
    sm[(c4 + 1) * 36 + col] = (a.x >> 16) | (v.x & 0xFFFF0000u);
    sm[(c4 + 2) * 36 + col] = (a.y & 0xFFFFu) | (v.y << 16);
    sm[(c4 + 3) * 36 + col] = (a.y >> 16) | (v.y & 0xFFFF0000u);
  }
  __syncthreads();
  u16* otb = xbfT + ((size_t)bp * 512 + e0) * 4096 + n0;
#pragma unroll
  for (int it = 0; it < 4; ++it) {
    const int e = it * 32 + (t >> 3);
    const int g = t & 7;  // npair group (4 dwords = 8 tokens)
    const int p4 = g * 4;
    const int sw = (e >> 2) & 15;
    const int base = e * 36 + (p4 & 16) + ((p4 ^ sw) & 12);
    uint4 v = *(const uint4*)&sm[base];
    const int s3 = sw & 3;
    unsigned q0 = v.x, q1 = v.y, q2 = v.z, q3 = v.w;
    if (s3 & 1) {
      unsigned tmp = q0; q0 = q1; q1 = tmp;
      tmp = q2; q2 = q3; q3 = tmp;
    }
    if (s3 & 2) {
      unsigned tmp = q0; q0 = q2; q2 = tmp;
      tmp = q1; q1 = q3; q3 = tmp;
    }
    uint4 o;
    o.x = q0; o.y = q1; o.z = q2; o.w = q3;
    *(uint4*)(otb + (size_t)e * 4096 + g * 8) = o;
  }
}

// ---------------- WvT[i][c'] = w_qkv[1024+c'][i], bf16. grid 16 ----------------
__global__ __launch_bounds__(256) void transpose_wv(const float* __restrict__ wv,
                                                    u16* __restrict__ wvT) {
  __shared__ __align__(16) u16 sm[128 * 136];
  const int b = blockIdx.x;
  const int r0 = (b >> 2) * 128;  // c' rows
  const int c0 = (b & 3) * 128;   // i cols
  const int t = threadIdx.x;
  const int rsub = t >> 5, c4 = (t & 31) * 4;
#pragma unroll
  for (int j = 0; j < 16; ++j) {
    const int r = j * 8 + rsub;
    float4 v = *(const float4*)(wv + (size_t)(r0 + r) * 512 + c0 + c4);
    sm[(c4 + 0) * 136 + ((j ^ ((c4 + 0) & 15)) << 3) + rsub] = f2bf(v.x);
    sm[(c4 + 1) * 136 + ((j ^ ((c4 + 1) & 15)) << 3) + rsub] = f2bf(v.y);
    sm[(c4 + 2) * 136 + ((j ^ ((c4 + 2) & 15)) << 3) + rsub] = f2bf(v.z);
    sm[(c4 + 3) * 136 + ((j ^ ((c4 + 3) & 15)) << 3) + rsub] = f2bf(v.w);
  }
  __syncthreads();
#pragma unroll
  for (int j = 0; j < 8; ++j) {
    const int re = j * 16 + (t >> 4);
    const int ct8 = t & 15;
    uint4 v = *(const uint4*)&sm[re * 136 + ((ct8 ^ (re & 15)) << 3)];
    *(uint4*)(wvT + (size_t)(c0 + re) * 512 + r0 + ct8 * 8) = v;
  }
}

// ---------------- generic C = A * B^T gemm, 128^2 tile, BK=64 K-steps ------------
// Two 32-wide LDS slabs per operand per step (4 slabs x 8KB = 32KB <= 34816B);
// one barrier pair per 64-K step (half the drains of BK=32).
// MODE 0: S partials, SYMMETRIC. grid dim3(40,16): bx = pair*4+kc, by = bp.
//         10 upper-triangle tiles; off-diagonal blocks write both mirrors (NT).
// MODE 1: P = Wqk*(S_hi then S_lo). grid 512. K=2x512. out bf16 P[bp][c][i].
// MODE 2: M = Weff[bp]*WvT^T. grid 256. out bf16 M[bp][co][i].
// MODE 3: y = M[bp]*x_bf[bp]^T + yb[bp]. grid 2048 (XCD-swizzled token tiles).
//         out fp32 y[bp][tok][co] (LDS-transposed store, NT).
template <int MODE>
__global__ __launch_bounds__(256) void gemm5(const u16* __restrict__ gA,
                                             const u16* __restrict__ gB,
                                             const float* __restrict__ bias,
                                             void* __restrict__ gC) {
  __shared__ __align__(16) u16 smem[128 * 136];  // 34816 B
  u16* As0 = smem;          // k half 0
  u16* As1 = smem + 4096;   // k half 1
  u16* Bs0 = smem + 8192;
  u16* Bs1 = smem + 12288;
  const int t = threadIdx.x;
  const int w = t >> 6, l = t & 63;
  const int lrow = l & 15, quad = l >> 4;
  const int wm = (w >> 1) * 64, wn = (w & 1) * 64;
  int m0, n0, bp = 0, kc = 0;
  if (MODE == 0) {
    const int bx = blockIdx.x;  // 0..39
    bp = blockIdx.y;
    kc = bx & 3;
    const int p = bx >> 2;  // 0..9 upper-triangle pair
    int ti, tj;
    if (p < 4) { ti = 0; tj = p; }
    else if (p < 7) { ti = 1; tj = p - 3; }
    else if (p < 9) { ti = 2; tj = p - 5; }
    else { ti = 3; tj = 3; }
    m0 = ti * 128;
    n0 = tj * 128;
  } else if (MODE == 1) {
    const int b = blockIdx.x;
    bp = b >> 5;
    const int tl = b & 31;
    m0 = (tl >> 2) * 128;
    n0 = (tl & 3) * 128;
  } else if (MODE == 2) {
    const int b = blockIdx.x;
    bp = b >> 4;
    const int tl = b & 15;
    m0 = (tl >> 2) * 128;
    n0 = (tl & 3) * 128;
  } else {
    const int b = blockIdx.x;
    const int local = b & 127;
    bp = b >> 7;
    const int j = (local >> 3) & 3;
    const int T = ((local >> 5) << 3) | (local & 7);  // token tile 0..31, id%8 locality
    m0 = j * 128;
    n0 = T * 128;
  }
  constexpr int LDA = (MODE == 0) ? 4096 : 512;
  constexpr int LDB = (MODE == 0) ? 4096 : 512;
  const u16* pA = gA;
  const u16* pB = gB;
  if (MODE == 0) {
    pA += (size_t)bp * (512 * 4096);
    pB = pA;
  } else if (MODE == 1) {
    pB += (size_t)bp * (512 * 512);
  } else if (MODE == 2) {
    pA += (size_t)bp * (512 * 512);
  } else {
    pA += (size_t)bp * (512 * 512);
    pB += (size_t)bp * (4096 * 512);
  }
  const int srow = w * 32 + (l >> 2);
  const int scol = (l & 3) * 8;
  const int koff = (MODE == 0) ? kc * 1024 : 0;
  const u16* ga0 = pA + (size_t)(m0 + srow) * LDA + scol + koff;
  const u16* ga1 = ga0 + (size_t)16 * LDA;
  const u16* gb0 = pB + (size_t)(n0 + srow) * LDB + scol + koff;
  const u16* gb1 = gb0 + (size_t)16 * LDB;
  u16* lA0a = &As0[w * 1024];
  u16* lA0b = lA0a + 512;
  u16* lA1a = &As1[w * 1024];
  u16* lA1b = lA1a + 512;
  u16* lB0a = &Bs0[w * 1024];
  u16* lB0b = lB0a + 512;
  u16* lB1a = &Bs1[w * 1024];
  u16* lB1b = lB1a + 512;

  f32x4 acc[4][4];
#pragma unroll
  for (int mi = 0; mi < 4; ++mi)
#pragma unroll
    for (int ni = 0; ni < 4; ++ni) acc[mi][ni] = (f32x4){0.f, 0.f, 0.f, 0.f};

  constexpr int KLEN = (MODE == 0) ? 1024 : 512;
  constexpr int NPH = (MODE == 1) ? 2 : 1;
#pragma unroll 1
  for (int ph = 0; ph < NPH; ++ph) {
    const size_t boff = (MODE == 1) ? (size_t)ph * 4194304 : 0;  // S_lo follows S_hi
#pragma unroll 1
    for (int k0 = 0; k0 < KLEN; k0 += 64) {
      gload_lds16(lA0a, ga0 + k0);
      gload_lds16(lA0b, ga1 + k0);
      gload_lds16(lA1a, ga0 + k0 + 32);
      gload_lds16(lA1b, ga1 + k0 + 32);
      gload_lds16(lB0a, gb0 + boff + k0);
      gload_lds16(lB0b, gb1 + boff + k0);
      gload_lds16(lB1a, gb0 + boff + k0 + 32);
      gload_lds16(lB1b, gb1 + boff + k0 + 32);
      __syncthreads();
      // k half 0
      {
        bf16x8 af[4], bfr[4];
#pragma unroll
        for (int mi = 0; mi < 4; ++mi)
          af[mi] = *(const bf16x8*)&As0[(wm + mi * 16 + lrow) * 32 + quad * 8];
#pragma unroll
        for (int ni = 0; ni < 4; ++ni)
          bfr[ni] = *(const bf16x8*)&Bs0[(wn + ni * 16 + lrow) * 32 + quad * 8];
#pragma unroll
        for (int mi = 0; mi < 4; ++mi)
#pragma unroll
          for (int ni = 0; ni < 4; ++ni)
            acc[mi][ni] = __builtin_amdgcn_mfma_f32_16x16x32_bf16(af[mi], bfr[ni], acc[mi][ni], 0, 0, 0);
      }
      __builtin_amdgcn_sched_barrier(0);  // keep half-1 frags from hoisting (VGPR cap)
      // k half 1
      {
        bf16x8 af[4], bfr[4];
#pragma unroll
        for (int mi = 0; mi < 4; ++mi)
          af[mi] = *(const bf16x8*)&As1[(wm + mi * 16 + lrow) * 32 + quad * 8];
#pragma unroll
        for (int ni = 0; ni < 4; ++ni)
          bfr[ni] = *(const bf16x8*)&Bs1[(wn + ni * 16 + lrow) * 32 + quad * 8];
#pragma unroll
        for (int mi = 0; mi < 4; ++mi)
#pragma unroll
          for (int ni = 0; ni < 4; ++ni)
            acc[mi][ni] = __builtin_amdgcn_mfma_f32_16x16x32_bf16(af[mi], bfr[ni], acc[mi][ni], 0, 0, 0);
      }
      __syncthreads();
    }
  }

  // epilogue: D row (M-dim) = quad*4 + reg, col (N-dim) = lrow
  if (MODE == 0 || MODE == 3) {
    // fp32 transposed store via two half-tiles
    float* gCp;
    if (MODE == 0)
      gCp = (float*)gC + (size_t)(kc * 16 + bp) * 262144;
    else
      gCp = (float*)gC + (size_t)bp * (4096 * 512);
    float* fs = (float*)smem;
#pragma unroll
    for (int half = 0; half < 2; ++half) {
      if (half) __syncthreads();
#pragma unroll
      for (int mi = 0; mi < 4; ++mi) {
        const int mrow_l = wm + mi * 16 + quad * 4;
        float4 bb = {0.f, 0.f, 0.f, 0.f};
        if (MODE == 3) bb = *(const float4*)&bias[(size_t)bp * 512 + m0 + mrow_l];
#pragma unroll
        for (int ni = 0; ni < 4; ++ni) {
          const int ncol_l = wn + ni * 16 + lrow;
          if ((ncol_l >> 6) != half) continue;
          f32x4 v = acc[mi][ni];
          float4 o;
          o.x = v[0] + bb.x;
          o.y = v[1] + bb.y;
          o.z = v[2] + bb.z;
          o.w = v[3] + bb.w;
          *(float4*)&fs[(ncol_l & 63) * 136 + mrow_l] = o;
        }
      }
      __syncthreads();
      // store C^T: rows j = n0+ncol, cols i = m0+mrow  (tile (tj,ti) region)
#pragma unroll
      for (int j2 = 0; j2 < 4; ++j2) {
        const int g = j2 * 256 + t;
        const int r = g >> 4;
        const int c = (g & 15) * 8;
        float4 v0 = *(const float4*)&fs[r * 136 + c];
        float4 v1 = *(const float4*)&fs[r * 136 + c + 4];
        float* yp = gCp + ((size_t)(n0 + half * 64 + r) * 512 + m0 + c);
        nt_store_f4(yp, v0.x, v0.y, v0.z, v0.w);
        nt_store_f4(yp + 4, v1.x, v1.y, v1.z, v1.w);
      }
      // MODE 0 off-diagonal: also store C natural (tile (ti,tj) region) — the
      // mirror is bitwise-identical by symmetry of X^T X.
      if (MODE == 0 && m0 != n0) {
#pragma unroll
        for (int j2 = 0; j2 < 8; ++j2) {
          const int g = j2 * 256 + t;
          const int row = g >> 4;       // mrow 0..127
          const int cg = (g & 15) * 4;  // ncol group 0..60
          nt_store_f4(gCp + (size_t)(m0 + row) * 512 + n0 + half * 64 + cg,
                      fs[(cg + 0) * 136 + row], fs[(cg + 1) * 136 + row],
                      fs[(cg + 2) * 136 + row], fs[(cg + 3) * 136 + row]);
        }
      }
    }
  } else {
    // natural bf16 store [m][n]
    u16* gCp = (u16*)gC + ((MODE == 1) ? (size_t)bp * 524288 : (size_t)bp * 262144);
#pragma unroll
    for (int mi = 0; mi < 4; ++mi) {
      const int mrow_l = wm + mi * 16 + quad * 4;
#pragma unroll
      for (int ni = 0; ni < 4; ++ni) {
        const int ncol_l = wn + ni * 16 + lrow;
        f32x4 v = acc[mi][ni];
        smem[(mrow_l + 0) * 136 + ncol_l] = f2bf(v[0]);
        smem[(mrow_l + 1) * 136 + ncol_l] = f2bf(v[1]);
        smem[(mrow_l + 2) * 136 + ncol_l] = f2bf(v[2]);
        smem[(mrow_l + 3) * 136 + ncol_l] = f2bf(v[3]);
      }
    }
    __syncthreads();
#pragma unroll
    for (int j = 0; j < 8; ++j) {
      const int g = j * 256 + t;
      const int r = g >> 4;
      const int c = (g & 15) * 8;
      uint4 val = *(const uint4*)&smem[r * 136 + c];
      *(uint4*)(gCp + (size_t)(m0 + r) * 512 + n0 + c) = val;
    }
  }
}

// ---------------- Spart[4] -> S_hi + S_lo (bf16 split). grid 4096 ----------------
__global__ __launch_bounds__(256) void s4red(const float* __restrict__ Spart,
                                             u16* __restrict__ Shi) {
  const size_t i = ((size_t)blockIdx.x * 256 + threadIdx.x) * 4;
  if (i >= 4194304) return;
  float4 a = *(const float4*)(Spart + i);
  float4 b = *(const float4*)(Spart + 4194304 + i);
  float4 c = *(const float4*)(Spart + 2 * 4194304 + i);
  float4 d = *(const float4*)(Spart + 3 * 4194304 + i);
  float s0 = a.x + b.x + c.x + d.x;
  float s1 = a.y + b.y + c.y + d.y;
  float s2 = a.z + b.z + c.z + d.z;
  float s3 = a.w + b.w + c.w + d.w;
  u16 h0 = f2bf(s0), h1 = f2bf(s1), h2 = f2bf(s2), h3 = f2bf(s3);
  uint2 hp;
  hp.x = (unsigned)h0 | ((unsigned)h1 << 16);
  hp.y = (unsigned)h2 | ((unsigned)h3 << 16);
  *(uint2*)(Shi + i) = hp;
  uint2 lp;
  lp.x = (unsigned)f2bf(s0 - bf2f(h0)) | ((unsigned)f2bf(s1 - bf2f(h1)) << 16);
  lp.y = (unsigned)f2bf(s2 - bf2f(h2)) | ((unsigned)f2bf(s3 - bf2f(h3)) << 16);
  *(uint2*)(Shi + 4194304 + i) = lp;
}

__device__ __forceinline__ void bf8_expand(uint4 v, float* o) {
  o[0] = bf2f((u16)(v.x & 0xffff)); o[1] = bf2f((u16)(v.x >> 16));
  o[2] = bf2f((u16)(v.y & 0xffff)); o[3] = bf2f((u16)(v.y >> 16));
  o[4] = bf2f((u16)(v.z & 0xffff)); o[5] = bf2f((u16)(v.z >> 16));
  o[6] = bf2f((u16)(v.w & 0xffff)); o[7] = bf2f((u16)(v.w >> 16));
}

// ---------------- per-(bp,h): G = Pq.Wk^T + rank-1 bias terms, norms from
// diag dots, softmax, Weff.  grid 128 = 16bp x 8h, 512 threads ----------------
__global__ __launch_bounds__(512) void softmax_weff2(const u16* __restrict__ P,
                                                     const u16* __restrict__ wqkv,
                                                     const float* __restrict__ b_qkv,
                                                     const float* __restrict__ svec,
                                                     const float* __restrict__ temperature,
                                                     const u16* __restrict__ wout,
                                                     u16* __restrict__ Weff) {
  __shared__ __align__(16) float sattn[64 * 64];
  __shared__ __align__(16) u16 sattnT[64 * 64];
  __shared__ float ub[128], dq[128], rnA[128], bb[128];
  const int blk = blockIdx.x;
  const int bp = blk >> 3, h = blk & 7;
  const int t = threadIdx.x, w = t >> 6, l = t & 63;
  const int lrow = l & 15, quad = l >> 4;

  // phase A: Gmm[d][e] = sum_i P[h*64+d][i] * Wk[h*64+e][i]   (K=512)
  {
    const int mi = w >> 1;
    const int nip = (w & 1) * 2;
    const u16* arow = P + ((size_t)bp * 1024 + h * 64 + mi * 16 + lrow) * 512;
    const u16* brow0 = wqkv + ((size_t)(512 + h * 64 + nip * 16 + lrow)) * 512;
    const u16* brow1 = brow0 + 16 * 512;
    f32x4 c0 = (f32x4){0.f, 0.f, 0.f, 0.f};
    f32x4 c1 = (f32x4){0.f, 0.f, 0.f, 0.f};
#pragma unroll 1
    for (int ks = 0; ks < 16; ++ks) {
      const int ko = ks * 32 + quad * 8;
      bf16x8 a = *(const bf16x8*)(arow + ko);
      bf16x8 b0 = *(const bf16x8*)(brow0 + ko);
      bf16x8 b1 = *(const bf16x8*)(brow1 + ko);
      c0 = __builtin_amdgcn_mfma_f32_16x16x32_bf16(a, b0, c0, 0, 0, 0);
      c1 = __builtin_amdgcn_mfma_f32_16x16x32_bf16(a, b1, c1, 0, 0, 0);
    }
    const int drow = mi * 16 + quad * 4;
#pragma unroll
    for (int r = 0; r < 4; ++r) {
      sattn[(drow + r) * 64 + nip * 16 + lrow] = c0[r];
      sattn[(drow + r) * 64 + (nip + 1) * 16 + lrow] = c1[r];
    }
  }

  // phase B: dq[rr] = P[c].W[c] (quadratic term), ub[rr] = W[c].svec
  {
    const int rr = t >> 2, sub = t & 3;
    const int c = (rr < 64) ? (h * 64 + rr) : (512 + h * 64 + (rr - 64));
    const u16* prow = P + ((size_t)bp * 1024 + c) * 512 + sub * 128;
    const u16* wrow = wqkv + (size_t)c * 512 + sub * 128;
    const float* sv = svec + (size_t)bp * 512 + sub * 128;
    float accp = 0.f, accu = 0.f;
#pragma unroll 1
    for (int i = 0; i < 128; i += 8) {
      float pf[8], wf[8];
      bf8_expand(*(const uint4*)(prow + i), pf);
      bf8_expand(*(const uint4*)(wrow + i), wf);
      float4 s0 = *(const float4*)(sv + i);
      float4 s1 = *(const float4*)(sv + i + 4);
      accp += pf[0] * wf[0] + pf[1] * wf[1] + pf[2] * wf[2] + pf[3] * wf[3] +
              pf[4] * wf[4] + pf[5] * wf[5] + pf[6] * wf[6] + pf[7] * wf[7];
      accu += wf[0] * s0.x + wf[1] * s0.y + wf[2] * s0.z + wf[3] * s0.w +
              wf[4] * s1.x + wf[5] * s1.y + wf[6] * s1.z + wf[7] * s1.w;
    }
    accp += __shfl_xor(accp, 1);
    accp += __shfl_xor(accp, 2);
    accu += __shfl_xor(accu, 1);
    accu += __shfl_xor(accu, 2);
    if (sub == 0) {
      dq[rr] = accp;
      ub[rr] = accu;
    }
  }
  __syncthreads();

  // phase C: ssq = w^T S w + 2 b (w.s) + N b^2 -> reciprocal norms
  if (t < 128) {
    const int c = (t < 64) ? (h * 64 + t) : (512 + h * 64 + (t - 64));
    const float bc = b_qkv[c];
    const float ss = dq[t] + 2.f * bc * ub[t] + 4096.f * bc * bc;
    rnA[t] = 1.f / fmaxf(sqrtf(ss), 1e-12f);
    bb[t] = bc;
  }
  __syncthreads();

  // phase D: logits (+rank-1 bias terms), softmax over e, write attn^T bf16
  if (t < 64) {
    const int d = t;
    const float rq = rnA[d], uqv = ub[d], bq = bb[d];
    const float tmp = temperature[h];
    float mx = -1e30f;
    for (int e = 0; e < 64; ++e) {
      const int idx = (e + d) & 63;  // rotate to dodge bank conflicts
      const float bk = bb[64 + idx];
      float g = sattn[d * 64 + idx] + bq * ub[64 + idx] + bk * uqv + 4096.f * bq * bk;
      float v = g * rq * rnA[64 + idx] * tmp;
      sattn[d * 64 + idx] = v;
      mx = fmaxf(mx, v);
    }
    float s = 0.f;
    for (int e = 0; e < 64; ++e) {
      const int idx = (e + d) & 63;
      float p = __expf(sattn[d * 64 + idx] - mx);
      s += p;
      sattn[d * 64 + idx] = p;
    }
    const float inv = 1.f / s;
    for (int e = 0; e < 64; ++e) {
      const int idx = (e + d) & 63;
      sattnT[idx * 64 + d] = f2bf(sattn[d * 64 + idx] * inv);
    }
  }
  __syncthreads();

  // phase E: Weff_h: C[e][co] = sum_d attnT[e][d] * wout[co][h*64+d]
  bf16x8 a0[4], a1[4];
#pragma unroll
  for (int mi = 0; mi < 4; ++mi) {
    a0[mi] = *(const bf16x8*)&sattnT[(mi * 16 + lrow) * 64 + quad * 8];
    a1[mi] = *(const bf16x8*)&sattnT[(mi * 16 + lrow) * 64 + 32 + quad * 8];
  }
  u16* wb = Weff + ((size_t)bp * (512 * 512));
#pragma unroll 1
  for (int nb = 0; nb < 4; ++nb) {
    const int co = (w * 4 + nb) * 16 + lrow;
    const u16* wrow = wout + (size_t)co * 512 + h * 64;
    bf16x8 b0 = *(const bf16x8*)(wrow + quad * 8);
    bf16x8 b1 = *(const bf16x8*)(wrow + 32 + quad * 8);
#pragma unroll
    for (int mi = 0; mi < 4; ++mi) {
      f32x4 c = (f32x4){0.f, 0.f, 0.f, 0.f};
      c = __builtin_amdgcn_mfma_f32_16x16x32_bf16(a0[mi], b0, c, 0, 0, 0);
      c = __builtin_amdgcn_mfma_f32_16x16x32_bf16(a1[mi], b1, c, 0, 0, 0);
      const int e0 = mi * 16 + quad * 4;
      uint2 pk;
      pk.x = (unsigned)f2bf(c[0]) | ((unsigned)f2bf(c[1]) << 16);
      pk.y = (unsigned)f2bf(c[2]) | ((unsigned)f2bf(c[3]) << 16);
      *(uint2*)(wb + (size_t)co * 512 + h * 64 + e0) = pk;
    }
  }
}

// ---------------- yb[bp][co] = b_out[co] + sum_c' Weff[bp][co][c'] * b_v[c'] ----------------
__global__ __launch_bounds__(512) void yb_kernel(const u16* __restrict__ Weff,
                                                 const float* __restrict__ b_qkv,
                                                 const float* __restrict__ b_out,
                                                 float* __restrict__ yb) {
  const int bp = blockIdx.x, co = threadIdx.x;
  const u16* wr = Weff + ((size_t)bp * 512 + co) * 512;
  float s = b_out[co];
#pragma unroll 1
  for (int i = 0; i < 512; i += 8) {
    float wf[8];
    bf8_expand(*(const uint4*)(wr + i), wf);
    const float4 b0 = *(const float4*)(b_qkv + 1024 + i);
    const float4 b1 = *(const float4*)(b_qkv + 1024 + i + 4);
    s += wf[0] * b0.x + wf[1] * b0.y + wf[2] * b0.z + wf[3] * b0.w +
         wf[4] * b1.x + wf[5] * b1.y + wf[6] * b1.z + wf[7] * b1.w;
  }
  yb[(size_t)bp * 512 + co] = s;
}

extern "C" void kernel_launch(void* const* d_in, const int* in_sizes, int n_in,
                              void* d_out, int out_size, void* d_ws, size_t ws_size,
                              hipStream_t stream) {
  const float* x = (const float*)d_in[0];      // (4,4,4096,512)
  const float* w_qkv = (const float*)d_in[1];  // (1536,512)
  const float* b_qkv = (const float*)d_in[2];  // (1536)
  const float* temp = (const float*)d_in[3];   // (8,1,1)
  const float* w_out = (const float*)d_in[4];  // (512,512)
  const float* b_out = (const float*)d_in[5];  // (512)
  float* y = (float*)d_out;

  char* ws = (char*)d_ws;
  u16* x_bf = (u16*)(ws);                    //  67,108,864 B  [bp][n][E]
  u16* x_bfT = (u16*)(ws + 67108864);        //  67,108,864 B  [bp][E][n]
  u16* wqkv_bf = (u16*)(ws + 134217728);     //   1,572,864 B
  u16* wout_bf = (u16*)(ws + 135790592);     //     524,288 B
  u16* wvT_bf = (u16*)(ws + 136314880);      //     524,288 B  [i][c']
  u16* S_hi = (u16*)(ws + 136839168);        //   8,388,608 B  [bp][i][j]
  // S_lo lives at S_hi + 4194304 elems      //   8,388,608 B
  u16* P_bf = (u16*)(ws + 153616384);        //  16,777,216 B  [bp][c][i]
  u16* Weff = (u16*)(ws + 170393600);        //   8,388,608 B  [bp][co][c']
  u16* M_bf = (u16*)(ws + 178782208);        //   8,388,608 B  [bp][co][i]
  float* svec = (float*)(ws + 187170816);    //      32,768 B  [bp][i]
  float* yb = (float*)(ws + 187203584);      //      32,768 B  [bp][co]
  float* Spart = (float*)(ws + 187236352);   //  67,108,864 B  [kc][bp][j][i]

  hipMemsetAsync(svec, 0, 32768, stream);
  // x -> bf16 natural + column sums (pure stream), then bf16 -> bf16 transpose
  cast_x<<<1024, 256, 0, stream>>>(x, x_bf, svec);
  transpose_x<<<4096, 256, 0, stream>>>(x_bf, x_bfT);
  cast_f32_bf16<<<384, 256, 0, stream>>>(w_qkv, wqkv_bf, 786432 / 8);
  cast_f32_bf16<<<128, 256, 0, stream>>>(w_out, wout_bf, 262144 / 8);
  transpose_wv<<<16, 256, 0, stream>>>(w_qkv + 1024 * 512, wvT_bf);
  // S = X^T X per bp (symmetric: 10 upper-triangle tiles x 4 K-chunks), hi/lo split
  gemm5<0><<<dim3(40, 16), 256, 0, stream>>>(x_bfT, x_bfT, nullptr, Spart);
  s4red<<<4096, 256, 0, stream>>>(Spart, S_hi);
  // P = W_qk * (S_hi + S_lo)
  gemm5<1><<<512, 256, 0, stream>>>(wqkv_bf, S_hi, nullptr, P_bf);
  // Gram + norms + softmax + Weff
  softmax_weff2<<<128, 512, 0, stream>>>(P_bf, wqkv_bf, b_qkv, svec, temp, wout_bf, Weff);
  yb_kernel<<<16, 512, 0, stream>>>(Weff, b_qkv, b_out, yb);
  // M = Weff * Wv
  gemm5<2><<<256, 256, 0, stream>>>(Weff, wvT_bf, nullptr, M_bf);
  // y = X * M^T + yb
  gemm5<3><<<2048, 256, 0, stream>>>(M_bf, x_bf, yb, y);
}

// Round 7
// 513.105 us; speedup vs baseline: 1.0192x; 1.0192x over previous
//
#include <hip/hip_runtime.h>
#include <stdint.h>

typedef unsigned short u16;
typedef __bf16 bf16x8 __attribute__((ext_vector_type(8)));
typedef float f32x4 __attribute__((ext_vector_type(4)));

#define AS1 __attribute__((address_space(1)))
#define AS3 __attribute__((address_space(3)))

// async global->LDS, 16B per lane; LDS dest is wave-uniform base + lane*16
__device__ __forceinline__ void gload_lds16(u16* lds_wave_base, const u16* g) {
  __builtin_amdgcn_global_load_lds((AS1 void*)g, (AS3 void*)lds_wave_base, 16, 0, 0);
}

__device__ __forceinline__ u16 f2bf(float f) {  // RNE fp32->bf16
  unsigned int u = __float_as_uint(f);
  u += 0x7fffu + ((u >> 16) & 1u);
  return (u16)(u >> 16);
}
__device__ __forceinline__ float bf2f(u16 h) { return __uint_as_float(((unsigned)h) << 16); }

// ---------------- cast fp32 -> bf16, 8 elements/thread (weights) ----------------
__global__ void cast_f32_bf16(const float* __restrict__ in, u16* __restrict__ out, int n8) {
  int i = blockIdx.x * blockDim.x + threadIdx.x;
  if (i >= n8) return;
  const float4* p = (const float4*)in + (size_t)i * 2;
  float4 a = p[0], b = p[1];
  uint2 lo, hi;
  lo.x = (unsigned)f2bf(a.x) | ((unsigned)f2bf(a.y) << 16);
  lo.y = (unsigned)f2bf(a.z) | ((unsigned)f2bf(a.w) << 16);
  hi.x = (unsigned)f2bf(b.x) | ((unsigned)f2bf(b.y) << 16);
  hi.y = (unsigned)f2bf(b.z) | ((unsigned)f2bf(b.w) << 16);
  uint2* o = (uint2*)out + (size_t)i * 2;
  o[0] = lo;
  o[1] = hi;
}

// ---------------- cast half: x fp32 -> bf16 natural + column sums ----------------
// grid 1024 = 16bp x 64-token chunks. 64 lanes cover a full 512-ch row (2KB read,
// 1KB write, perfectly coalesced). Pure stream, no barrier in the hot loop.
__global__ __launch_bounds__(256) void cast_x(const float* __restrict__ x,
                                              u16* __restrict__ xbf,
                                              float* __restrict__ svec) {
  __shared__ float sred[4 * 512];  // 8 KB
  const int b = blockIdx.x;
  const int bp = b >> 6;
  const int n0 = (b & 63) * 64;
  const int t = threadIdx.x;
  const int e8 = (t & 63) * 8;
  const int r0 = t >> 6;  // 0..3
  const float* xb = x + ((size_t)(bp * 4096 + n0) * 512) + e8;
  u16* ob = xbf + ((size_t)(bp * 4096 + n0) * 512) + e8;
  float s0 = 0.f, s1 = 0.f, s2 = 0.f, s3 = 0.f, s4 = 0.f, s5 = 0.f, s6 = 0.f, s7 = 0.f;
#pragma unroll 2
  for (int pass = 0; pass < 16; ++pass) {
    const int r = pass * 4 + r0;
    const float* p = xb + (size_t)r * 512;
    float4 v0 = *(const float4*)p;
    float4 v1 = *(const float4*)(p + 4);
    uint2 lo, hi;
    lo.x = (unsigned)f2bf(v0.x) | ((unsigned)f2bf(v0.y) << 16);
    lo.y = (unsigned)f2bf(v0.z) | ((unsigned)f2bf(v0.w) << 16);
    hi.x = (unsigned)f2bf(v1.x) | ((unsigned)f2bf(v1.y) << 16);
    hi.y = (unsigned)f2bf(v1.z) | ((unsigned)f2bf(v1.w) << 16);
    uint2* o = (uint2*)(ob + (size_t)r * 512);
    o[0] = lo;
    o[1] = hi;
    s0 += v0.x; s1 += v0.y; s2 += v0.z; s3 += v0.w;
    s4 += v1.x; s5 += v1.y; s6 += v1.z; s7 += v1.w;
  }
  float* sp = &sred[r0 * 512 + e8];
  sp[0] = s0; sp[1] = s1; sp[2] = s2; sp[3] = s3;
  sp[4] = s4; sp[5] = s5; sp[6] = s6; sp[7] = s7;
  __syncthreads();
  // 512 channels / 256 threads = 2 each; sum the 4 row-groups, one atomic per ch
  {
    const int e = t * 2;
    float a0 = sred[e] + sred[512 + e] + sred[1024 + e] + sred[1536 + e];
    float a1 = sred[e + 1] + sred[512 + e + 1] + sred[1024 + e + 1] + sred[1536 + e + 1];
    float* sv = svec + (size_t)bp * 512 + e;
    atomicAdd(sv + 0, a0);
    atomicAdd(sv + 1, a1);
  }
}

// ---------------- transpose half: x_bf [bp][n][E] -> x_bfT [bp][E][n] ------------
// grid 4096 = 16bp x 64 tok-tiles(64) x 4 E-tiles(128). bf16-only traffic (134 MB).
// LDS: dword [e:128][npair:32] stride 36 dw, col = (np&16)|((np^((e>>2)&15))&15),
// dword packs tokens {2np,2np+1} at channel e (round-2 verified scheme).
// 18432 B LDS -> 8 blocks/CU; all 8 loads issued up front.
__global__ __launch_bounds__(256) void transpose_x(const u16* __restrict__ xbf,
                                                   u16* __restrict__ xbfT) {
  __shared__ __align__(16) unsigned sm[128 * 36];  // 18432 B
  const int b = blockIdx.x;
  const int bp = b >> 8;
  const int tt = (b >> 2) & 63;
  const int et = b & 3;
  const int t = threadIdx.x;
  const int n0 = tt * 64, e0 = et * 128;
  const int c4 = (t & 31) * 4;  // 4 channels; (e>>2)&15 == t&15
  const int pr = t >> 5;        // 0..7 token-pair row
  const int sw1 = t & 15;
  const u16* ib = xbf + ((size_t)(bp * 4096 + n0) * 512) + e0 + c4;
  // issue all 8 loads up front
  uint2 ta[4], tb[4];
#pragma unroll
  for (int jp = 0; jp < 4; ++jp) {
    const int n = (jp * 8 + pr) * 2;
    ta[jp] = *(const uint2*)(ib + (size_t)n * 512);
    tb[jp] = *(const uint2*)(ib + (size_t)(n + 1) * 512);
  }
#pragma unroll
  for (int jp = 0; jp < 4; ++jp) {
    const int npair = jp * 8 + pr;
    const uint2 a = ta[jp], v = tb[jp];
    const int col = (npair & 16) | ((npair ^ sw1) & 15);
    // dword k: lo16 = tok n ch c4+k, hi16 = tok n+1 ch c4+k
    sm[(c4 + 0) * 36 + col] = (a.x & 0xFFFFu) | (v.x << 16);
    sm[(c4 + 1) * 36 + col] = (a.x >> 16) | (v.x & 0xFFFF0000u);
    sm[(c4 + 2) * 36 + col] = (a.y & 0xFFFFu) | (v.y << 16);
    sm[(c4 + 3) * 36 + col] = (a.y >> 16) | (v.y & 0xFFFF0000u);
  }
  __syncthreads();
  u16* otb = xbfT + ((size_t)bp * 512 + e0) * 4096 + n0;
#pragma unroll
  for (int it = 0; it < 4; ++it) {
    const int e = it * 32 + (t >> 3);
    const int g = t & 7;  // npair group (4 dwords = 8 tokens)
    const int p4 = g * 4;
    const int sw = (e >> 2) & 15;
    const int base = e * 36 + (p4 & 16) + ((p4 ^ sw) & 12);
    uint4 v = *(const uint4*)&sm[base];
    const int s3 = sw & 3;
    unsigned q0 = v.x, q1 = v.y, q2 = v.z, q3 = v.w;
    if (s3 & 1) {
      unsigned tmp = q0; q0 = q1; q1 = tmp;
      tmp = q2; q2 = q3; q3 = tmp;
    }
    if (s3 & 2) {
      unsigned tmp = q0; q0 = q2; q2 = tmp;
      tmp = q1; q1 = q3; q3 = tmp;
    }
    uint4 o;
    o.x = q0; o.y = q1; o.z = q2; o.w = q3;
    *(uint4*)(otb + (size_t)e * 4096 + g * 8) = o;
  }
}

// ---------------- WvT[i][c'] = w_qkv[1024+c'][i], bf16. grid 16 ----------------
__global__ __launch_bounds__(256) void transpose_wv(const float* __restrict__ wv,
                                                    u16* __restrict__ wvT) {
  __shared__ __align__(16) u16 sm[128 * 136];
  const int b = blockIdx.x;
  const int r0 = (b >> 2) * 128;  // c' rows
  const int c0 = (b & 3) * 128;   // i cols
  const int t = threadIdx.x;
  const int rsub = t >> 5, c4 = (t & 31) * 4;
#pragma unroll
  for (int j = 0; j < 16; ++j) {
    const int r = j * 8 + rsub;
    float4 v = *(const float4*)(wv + (size_t)(r0 + r) * 512 + c0 + c4);
    sm[(c4 + 0) * 136 + ((j ^ ((c4 + 0) & 15)) << 3) + rsub] = f2bf(v.x);
    sm[(c4 + 1) * 136 + ((j ^ ((c4 + 1) & 15)) << 3) + rsub] = f2bf(v.y);
    sm[(c4 + 2) * 136 + ((j ^ ((c4 + 2) & 15)) << 3) + rsub] = f2bf(v.z);
    sm[(c4 + 3) * 136 + ((j ^ ((c4 + 3) & 15)) << 3) + rsub] = f2bf(v.w);
  }
  __syncthreads();
#pragma unroll
  for (int j = 0; j < 8; ++j) {
    const int re = j * 16 + (t >> 4);
    const int ct8 = t & 15;
    uint4 v = *(const uint4*)&sm[re * 136 + ((ct8 ^ (re & 15)) << 3)];
    *(uint4*)(wvT + (size_t)(c0 + re) * 512 + r0 + ct8 * 8) = v;
  }
}

// ---------------- generic C = A * B^T gemm, 128^2 tile, BK=64 K-steps ------------
// Two 32-wide LDS slabs per operand per step (4 slabs x 8KB = 32KB <= 34816B);
// one barrier pair per 64-K step (half the drains of BK=32). Plain cached stores
// (NT regressed: +58MB HBM write amplification, round-5).
// MODE 0: S partials, SYMMETRIC. grid dim3(40,16): bx = pair*4+kc, by = bp.
//         10 upper-triangle tiles; off-diagonal blocks write both mirrors.
// MODE 1: P = Wqk*(S_hi then S_lo). grid 512. K=2x512. out bf16 P[bp][c][i].
// MODE 2: M = Weff[bp]*WvT^T. grid 256. out bf16 M[bp][co][i].
// MODE 3: y = M[bp]*x_bf[bp]^T + yb[bp]. grid 2048 (XCD-swizzled token tiles).
//         out fp32 y[bp][tok][co] (LDS-transposed store).
template <int MODE>
__global__ __launch_bounds__(256) void gemm5(const u16* __restrict__ gA,
                                             const u16* __restrict__ gB,
                                             const float* __restrict__ bias,
                                             void* __restrict__ gC) {
  __shared__ __align__(16) u16 smem[128 * 136];  // 34816 B
  u16* As0 = smem;          // k half 0
  u16* As1 = smem + 4096;   // k half 1
  u16* Bs0 = smem + 8192;
  u16* Bs1 = smem + 12288;
  const int t = threadIdx.x;
  const int w = t >> 6, l = t & 63;
  const int lrow = l & 15, quad = l >> 4;
  const int wm = (w >> 1) * 64, wn = (w & 1) * 64;
  int m0, n0, bp = 0, kc = 0;
  if (MODE == 0) {
    const int bx = blockIdx.x;  // 0..39
    bp = blockIdx.y;
    kc = bx & 3;
    const int p = bx >> 2;  // 0..9 upper-triangle pair
    int ti, tj;
    if (p < 4) { ti = 0; tj = p; }
    else if (p < 7) { ti = 1; tj = p - 3; }
    else if (p < 9) { ti = 2; tj = p - 5; }
    else { ti = 3; tj = 3; }
    m0 = ti * 128;
    n0 = tj * 128;
  } else if (MODE == 1) {
    const int b = blockIdx.x;
    bp = b >> 5;
    const int tl = b & 31;
    m0 = (tl >> 2) * 128;
    n0 = (tl & 3) * 128;
  } else if (MODE == 2) {
    const int b = blockIdx.x;
    bp = b >> 4;
    const int tl = b & 15;
    m0 = (tl >> 2) * 128;
    n0 = (tl & 3) * 128;
  } else {
    const int b = blockIdx.x;
    const int local = b & 127;
    bp = b >> 7;
    const int j = (local >> 3) & 3;
    const int T = ((local >> 5) << 3) | (local & 7);  // token tile 0..31, id%8 locality
    m0 = j * 128;
    n0 = T * 128;
  }
  constexpr int LDA = (MODE == 0) ? 4096 : 512;
  constexpr int LDB = (MODE == 0) ? 4096 : 512;
  const u16* pA = gA;
  const u16* pB = gB;
  if (MODE == 0) {
    pA += (size_t)bp * (512 * 4096);
    pB = pA;
  } else if (MODE == 1) {
    pB += (size_t)bp * (512 * 512);
  } else if (MODE == 2) {
    pA += (size_t)bp * (512 * 512);
  } else {
    pA += (size_t)bp * (512 * 512);
    pB += (size_t)bp * (4096 * 512);
  }
  const int srow = w * 32 + (l >> 2);
  const int scol = (l & 3) * 8;
  const int koff = (MODE == 0) ? kc * 1024 : 0;
  const u16* ga0 = pA + (size_t)(m0 + srow) * LDA + scol + koff;
  const u16* ga1 = ga0 + (size_t)16 * LDA;
  const u16* gb0 = pB + (size_t)(n0 + srow) * LDB + scol + koff;
  const u16* gb1 = gb0 + (size_t)16 * LDB;
  u16* lA0a = &As0[w * 1024];
  u16* lA0b = lA0a + 512;
  u16* lA1a = &As1[w * 1024];
  u16* lA1b = lA1a + 512;
  u16* lB0a = &Bs0[w * 1024];
  u16* lB0b = lB0a + 512;
  u16* lB1a = &Bs1[w * 1024];
  u16* lB1b = lB1a + 512;

  f32x4 acc[4][4];
#pragma unroll
  for (int mi = 0; mi < 4; ++mi)
#pragma unroll
    for (int ni = 0; ni < 4; ++ni) acc[mi][ni] = (f32x4){0.f, 0.f, 0.f, 0.f};

  constexpr int KLEN = (MODE == 0) ? 1024 : 512;
  constexpr int NPH = (MODE == 1) ? 2 : 1;
#pragma unroll 1
  for (int ph = 0; ph < NPH; ++ph) {
    const size_t boff = (MODE == 1) ? (size_t)ph * 4194304 : 0;  // S_lo follows S_hi
#pragma unroll 1
    for (int k0 = 0; k0 < KLEN; k0 += 64) {
      gload_lds16(lA0a, ga0 + k0);
      gload_lds16(lA0b, ga1 + k0);
      gload_lds16(lA1a, ga0 + k0 + 32);
      gload_lds16(lA1b, ga1 + k0 + 32);
      gload_lds16(lB0a, gb0 + boff + k0);
      gload_lds16(lB0b, gb1 + boff + k0);
      gload_lds16(lB1a, gb0 + boff + k0 + 32);
      gload_lds16(lB1b, gb1 + boff + k0 + 32);
      __syncthreads();
      // k half 0
      {
        bf16x8 af[4], bfr[4];
#pragma unroll
        for (int mi = 0; mi < 4; ++mi)
          af[mi] = *(const bf16x8*)&As0[(wm + mi * 16 + lrow) * 32 + quad * 8];
#pragma unroll
        for (int ni = 0; ni < 4; ++ni)
          bfr[ni] = *(const bf16x8*)&Bs0[(wn + ni * 16 + lrow) * 32 + quad * 8];
#pragma unroll
        for (int mi = 0; mi < 4; ++mi)
#pragma unroll
          for (int ni = 0; ni < 4; ++ni)
            acc[mi][ni] = __builtin_amdgcn_mfma_f32_16x16x32_bf16(af[mi], bfr[ni], acc[mi][ni], 0, 0, 0);
      }
      __builtin_amdgcn_sched_barrier(0);  // keep half-1 frags from hoisting (VGPR cap)
      // k half 1
      {
        bf16x8 af[4], bfr[4];
#pragma unroll
        for (int mi = 0; mi < 4; ++mi)
          af[mi] = *(const bf16x8*)&As1[(wm + mi * 16 + lrow) * 32 + quad * 8];
#pragma unroll
        for (int ni = 0; ni < 4; ++ni)
          bfr[ni] = *(const bf16x8*)&Bs1[(wn + ni * 16 + lrow) * 32 + quad * 8];
#pragma unroll
        for (int mi = 0; mi < 4; ++mi)
#pragma unroll
          for (int ni = 0; ni < 4; ++ni)
            acc[mi][ni] = __builtin_amdgcn_mfma_f32_16x16x32_bf16(af[mi], bfr[ni], acc[mi][ni], 0, 0, 0);
      }
      __syncthreads();
    }
  }

  // epilogue: D row (M-dim) = quad*4 + reg, col (N-dim) = lrow
  if (MODE == 0 || MODE == 3) {
    // fp32 transposed store via two half-tiles
    float* gCp;
    if (MODE == 0)
      gCp = (float*)gC + (size_t)(kc * 16 + bp) * 262144;
    else
      gCp = (float*)gC + (size_t)bp * (4096 * 512);
    float* fs = (float*)smem;
#pragma unroll
    for (int half = 0; half < 2; ++half) {
      if (half) __syncthreads();
#pragma unroll
      for (int mi = 0; mi < 4; ++mi) {
        const int mrow_l = wm + mi * 16 + quad * 4;
        float4 bb = {0.f, 0.f, 0.f, 0.f};
        if (MODE == 3) bb = *(const float4*)&bias[(size_t)bp * 512 + m0 + mrow_l];
#pragma unroll
        for (int ni = 0; ni < 4; ++ni) {
          const int ncol_l = wn + ni * 16 + lrow;
          if ((ncol_l >> 6) != half) continue;
          f32x4 v = acc[mi][ni];
          float4 o;
          o.x = v[0] + bb.x;
          o.y = v[1] + bb.y;
          o.z = v[2] + bb.z;
          o.w = v[3] + bb.w;
          *(float4*)&fs[(ncol_l & 63) * 136 + mrow_l] = o;
        }
      }
      __syncthreads();
      // store C^T: rows j = n0+ncol, cols i = m0+mrow  (tile (tj,ti) region)
#pragma unroll
      for (int j2 = 0; j2 < 4; ++j2) {
        const int g = j2 * 256 + t;
        const int r = g >> 4;
        const int c = (g & 15) * 8;
        float4 v0 = *(const float4*)&fs[r * 136 + c];
        float4 v1 = *(const float4*)&fs[r * 136 + c + 4];
        float* yp = gCp + ((size_t)(n0 + half * 64 + r) * 512 + m0 + c);
        *(float4*)yp = v0;
        *(float4*)(yp + 4) = v1;
      }
      // MODE 0 off-diagonal: also store C natural (tile (ti,tj) region) — the
      // mirror is bitwise-identical by symmetry of X^T X.
      if (MODE == 0 && m0 != n0) {
#pragma unroll
        for (int j2 = 0; j2 < 8; ++j2) {
          const int g = j2 * 256 + t;
          const int row = g >> 4;       // mrow 0..127
          const int cg = (g & 15) * 4;  // ncol group 0..60
          float4 o;
          o.x = fs[(cg + 0) * 136 + row];
          o.y = fs[(cg + 1) * 136 + row];
          o.z = fs[(cg + 2) * 136 + row];
          o.w = fs[(cg + 3) * 136 + row];
          *(float4*)(gCp + (size_t)(m0 + row) * 512 + n0 + half * 64 + cg) = o;
        }
      }
    }
  } else {
    // natural bf16 store [m][n]
    u16* gCp = (u16*)gC + ((MODE == 1) ? (size_t)bp * 524288 : (size_t)bp * 262144);
#pragma unroll
    for (int mi = 0; mi < 4; ++mi) {
      const int mrow_l = wm + mi * 16 + quad * 4;
#pragma unroll
      for (int ni = 0; ni < 4; ++ni) {
        const int ncol_l = wn + ni * 16 + lrow;
        f32x4 v = acc[mi][ni];
        smem[(mrow_l + 0) * 136 + ncol_l] = f2bf(v[0]);
        smem[(mrow_l + 1) * 136 + ncol_l] = f2bf(v[1]);
        smem[(mrow_l + 2) * 136 + ncol_l] = f2bf(v[2]);
        smem[(mrow_l + 3) * 136 + ncol_l] = f2bf(v[3]);
      }
    }
    __syncthreads();
#pragma unroll
    for (int j = 0; j < 8; ++j) {
      const int g = j * 256 + t;
      const int r = g >> 4;
      const int c = (g & 15) * 8;
      uint4 val = *(const uint4*)&smem[r * 136 + c];
      *(uint4*)(gCp + (size_t)(m0 + r) * 512 + n0 + c) = val;
    }
  }
}

// ---------------- Spart[4] -> S_hi + S_lo (bf16 split). grid 4096 ----------------
__global__ __launch_bounds__(256) void s4red(const float* __restrict__ Spart,
                                             u16* __restrict__ Shi) {
  const size_t i = ((size_t)blockIdx.x * 256 + threadIdx.x) * 4;
  if (i >= 4194304) return;
  float4 a = *(const float4*)(Spart + i);
  float4 b = *(const float4*)(Spart + 4194304 + i);
  float4 c = *(const float4*)(Spart + 2 * 4194304 + i);
  float4 d = *(const float4*)(Spart + 3 * 4194304 + i);
  float s0 = a.x + b.x + c.x + d.x;
  float s1 = a.y + b.y + c.y + d.y;
  float s2 = a.z + b.z + c.z + d.z;
  float s3 = a.w + b.w + c.w + d.w;
  u16 h0 = f2bf(s0), h1 = f2bf(s1), h2 = f2bf(s2), h3 = f2bf(s3);
  uint2 hp;
  hp.x = (unsigned)h0 | ((unsigned)h1 << 16);
  hp.y = (unsigned)h2 | ((unsigned)h3 << 16);
  *(uint2*)(Shi + i) = hp;
  uint2 lp;
  lp.x = (unsigned)f2bf(s0 - bf2f(h0)) | ((unsigned)f2bf(s1 - bf2f(h1)) << 16);
  lp.y = (unsigned)f2bf(s2 - bf2f(h2)) | ((unsigned)f2bf(s3 - bf2f(h3)) << 16);
  *(uint2*)(Shi + 4194304 + i) = lp;
}

__device__ __forceinline__ void bf8_expand(uint4 v, float* o) {
  o[0] = bf2f((u16)(v.x & 0xffff)); o[1] = bf2f((u16)(v.x >> 16));
  o[2] = bf2f((u16)(v.y & 0xffff)); o[3] = bf2f((u16)(v.y >> 16));
  o[4] = bf2f((u16)(v.z & 0xffff)); o[5] = bf2f((u16)(v.z >> 16));
  o[6] = bf2f((u16)(v.w & 0xffff)); o[7] = bf2f((u16)(v.w >> 16));
}

// ---------------- per-(bp,h): G = Pq.Wk^T + rank-1 bias terms, norms from
// diag dots, softmax, Weff.  grid 128 = 16bp x 8h, 512 threads ----------------
__global__ __launch_bounds__(512) void softmax_weff2(const u16* __restrict__ P,
                                                     const u16* __restrict__ wqkv,
                                                     const float* __restrict__ b_qkv,
                                                     const float* __restrict__ svec,
                                                     const float* __restrict__ temperature,
                                                     const u16* __restrict__ wout,
                                                     u16* __restrict__ Weff) {
  __shared__ __align__(16) float sattn[64 * 64];
  __shared__ __align__(16) u16 sattnT[64 * 64];
  __shared__ float ub[128], dq[128], rnA[128], bb[128];
  const int blk = blockIdx.x;
  const int bp = blk >> 3, h = blk & 7;
  const int t = threadIdx.x, w = t >> 6, l = t & 63;
  const int lrow = l & 15, quad = l >> 4;

  // phase A: Gmm[d][e] = sum_i P[h*64+d][i] * Wk[h*64+e][i]   (K=512)
  {
    const int mi = w >> 1;
    const int nip = (w & 1) * 2;
    const u16* arow = P + ((size_t)bp * 1024 + h * 64 + mi * 16 + lrow) * 512;
    const u16* brow0 = wqkv + ((size_t)(512 + h * 64 + nip * 16 + lrow)) * 512;
    const u16* brow1 = brow0 + 16 * 512;
    f32x4 c0 = (f32x4){0.f, 0.f, 0.f, 0.f};
    f32x4 c1 = (f32x4){0.f, 0.f, 0.f, 0.f};
#pragma unroll 1
    for (int ks = 0; ks < 16; ++ks) {
      const int ko = ks * 32 + quad * 8;
      bf16x8 a = *(const bf16x8*)(arow + ko);
      bf16x8 b0 = *(const bf16x8*)(brow0 + ko);
      bf16x8 b1 = *(const bf16x8*)(brow1 + ko);
      c0 = __builtin_amdgcn_mfma_f32_16x16x32_bf16(a, b0, c0, 0, 0, 0);
      c1 = __builtin_amdgcn_mfma_f32_16x16x32_bf16(a, b1, c1, 0, 0, 0);
    }
    const int drow = mi * 16 + quad * 4;
#pragma unroll
    for (int r = 0; r < 4; ++r) {
      sattn[(drow + r) * 64 + nip * 16 + lrow] = c0[r];
      sattn[(drow + r) * 64 + (nip + 1) * 16 + lrow] = c1[r];
    }
  }

  // phase B: dq[rr] = P[c].W[c] (quadratic term), ub[rr] = W[c].svec
  {
    const int rr = t >> 2, sub = t & 3;
    const int c = (rr < 64) ? (h * 64 + rr) : (512 + h * 64 + (rr - 64));
    const u16* prow = P + ((size_t)bp * 1024 + c) * 512 + sub * 128;
    const u16* wrow = wqkv + (size_t)c * 512 + sub * 128;
    const float* sv = svec + (size_t)bp * 512 + sub * 128;
    float accp = 0.f, accu = 0.f;
#pragma unroll 1
    for (int i = 0; i < 128; i += 8) {
      float pf[8], wf[8];
      bf8_expand(*(const uint4*)(prow + i), pf);
      bf8_expand(*(const uint4*)(wrow + i), wf);
      float4 s0 = *(const float4*)(sv + i);
      float4 s1 = *(const float4*)(sv + i + 4);
      accp += pf[0] * wf[0] + pf[1] * wf[1] + pf[2] * wf[2] + pf[3] * wf[3] +
              pf[4] * wf[4] + pf[5] * wf[5] + pf[6] * wf[6] + pf[7] * wf[7];
      accu += wf[0] * s0.x + wf[1] * s0.y + wf[2] * s0.z + wf[3] * s0.w +
              wf[4] * s1.x + wf[5] * s1.y + wf[6] * s1.z + wf[7] * s1.w;
    }
    accp += __shfl_xor(accp, 1);
    accp += __shfl_xor(accp, 2);
    accu += __shfl_xor(accu, 1);
    accu += __shfl_xor(accu, 2);
    if (sub == 0) {
      dq[rr] = accp;
      ub[rr] = accu;
    }
  }
  __syncthreads();

  // phase C: ssq = w^T S w + 2 b (w.s) + N b^2 -> reciprocal norms
  if (t < 128) {
    const int c = (t < 64) ? (h * 64 + t) : (512 + h * 64 + (t - 64));
    const float bc = b_qkv[c];
    const float ss = dq[t] + 2.f * bc * ub[t] + 4096.f * bc * bc;
    rnA[t] = 1.f / fmaxf(sqrtf(ss), 1e-12f);
    bb[t] = bc;
  }
  __syncthreads();

  // phase D: logits (+rank-1 bias terms), softmax over e, write attn^T bf16
  if (t < 64) {
    const int d = t;
    const float rq = rnA[d], uqv = ub[d], bq = bb[d];
    const float tmp = temperature[h];
    float mx = -1e30f;
    for (int e = 0; e < 64; ++e) {
      const int idx = (e + d) & 63;  // rotate to dodge bank conflicts
      const float bk = bb[64 + idx];
      float g = sattn[d * 64 + idx] + bq * ub[64 + idx] + bk * uqv + 4096.f * bq * bk;
      float v = g * rq * rnA[64 + idx] * tmp;
      sattn[d * 64 + idx] = v;
      mx = fmaxf(mx, v);
    }
    float s = 0.f;
    for (int e = 0; e < 64; ++e) {
      const int idx = (e + d) & 63;
      float p = __expf(sattn[d * 64 + idx] - mx);
      s += p;
      sattn[d * 64 + idx] = p;
    }
    const float inv = 1.f / s;
    for (int e = 0; e < 64; ++e) {
      const int idx = (e + d) & 63;
      sattnT[idx * 64 + d] = f2bf(sattn[d * 64 + idx] * inv);
    }
  }
  __syncthreads();

  // phase E: Weff_h: C[e][co] = sum_d attnT[e][d] * wout[co][h*64+d]
  bf16x8 a0[4], a1[4];
#pragma unroll
  for (int mi = 0; mi < 4; ++mi) {
    a0[mi] = *(const bf16x8*)&sattnT[(mi * 16 + lrow) * 64 + quad * 8];
    a1[mi] = *(const bf16x8*)&sattnT[(mi * 16 + lrow) * 64 + 32 + quad * 8];
  }
  u16* wb = Weff + ((size_t)bp * (512 * 512));
#pragma unroll 1
  for (int nb = 0; nb < 4; ++nb) {
    const int co = (w * 4 + nb) * 16 + lrow;
    const u16* wrow = wout + (size_t)co * 512 + h * 64;
    bf16x8 b0 = *(const bf16x8*)(wrow + quad * 8);
    bf16x8 b1 = *(const bf16x8*)(wrow + 32 + quad * 8);
#pragma unroll
    for (int mi = 0; mi < 4; ++mi) {
      f32x4 c = (f32x4){0.f, 0.f, 0.f, 0.f};
      c = __builtin_amdgcn_mfma_f32_16x16x32_bf16(a0[mi], b0, c, 0, 0, 0);
      c = __builtin_amdgcn_mfma_f32_16x16x32_bf16(a1[mi], b1, c, 0, 0, 0);
      const int e0 = mi * 16 + quad * 4;
      uint2 pk;
      pk.x = (unsigned)f2bf(c[0]) | ((unsigned)f2bf(c[1]) << 16);
      pk.y = (unsigned)f2bf(c[2]) | ((unsigned)f2bf(c[3]) << 16);
      *(uint2*)(wb + (size_t)co * 512 + h * 64 + e0) = pk;
    }
  }
}

// ---------------- yb[bp][co] = b_out[co] + sum_c' Weff[bp][co][c'] * b_v[c'] ----------------
__global__ __launch_bounds__(512) void yb_kernel(const u16* __restrict__ Weff,
                                                 const float* __restrict__ b_qkv,
                                                 const float* __restrict__ b_out,
                                                 float* __restrict__ yb) {
  const int bp = blockIdx.x, co = threadIdx.x;
  const u16* wr = Weff + ((size_t)bp * 512 + co) * 512;
  float s = b_out[co];
#pragma unroll 1
  for (int i = 0; i < 512; i += 8) {
    float wf[8];
    bf8_expand(*(const uint4*)(wr + i), wf);
    const float4 b0 = *(const float4*)(b_qkv + 1024 + i);
    const float4 b1 = *(const float4*)(b_qkv + 1024 + i + 4);
    s += wf[0] * b0.x + wf[1] * b0.y + wf[2] * b0.z + wf[3] * b0.w +
         wf[4] * b1.x + wf[5] * b1.y + wf[6] * b1.z + wf[7] * b1.w;
  }
  yb[(size_t)bp * 512 + co] = s;
}

extern "C" void kernel_launch(void* const* d_in, const int* in_sizes, int n_in,
                              void* d_out, int out_size, void* d_ws, size_t ws_size,
                              hipStream_t stream) {
  const float* x = (const float*)d_in[0];      // (4,4,4096,512)
  const float* w_qkv = (const float*)d_in[1];  // (1536,512)
  const float* b_qkv = (const float*)d_in[2];  // (1536)
  const float* temp = (const float*)d_in[3];   // (8,1,1)
  const float* w_out = (const float*)d_in[4];  // (512,512)
  const float* b_out = (const float*)d_in[5];  // (512)
  float* y = (float*)d_out;

  char* ws = (char*)d_ws;
  u16* x_bf = (u16*)(ws);                    //  67,108,864 B  [bp][n][E]
  u16* x_bfT = (u16*)(ws + 67108864);        //  67,108,864 B  [bp][E][n]
  u16* wqkv_bf = (u16*)(ws + 134217728);     //   1,572,864 B
  u16* wout_bf = (u16*)(ws + 135790592);     //     524,288 B
  u16* wvT_bf = (u16*)(ws + 136314880);      //     524,288 B  [i][c']
  u16* S_hi = (u16*)(ws + 136839168);        //   8,388,608 B  [bp][i][j]
  // S_lo lives at S_hi + 4194304 elems      //   8,388,608 B
  u16* P_bf = (u16*)(ws + 153616384);        //  16,777,216 B  [bp][c][i]
  u16* Weff = (u16*)(ws + 170393600);        //   8,388,608 B  [bp][co][c']
  u16* M_bf = (u16*)(ws + 178782208);        //   8,388,608 B  [bp][co][i]
  float* svec = (float*)(ws + 187170816);    //      32,768 B  [bp][i]
  float* yb = (float*)(ws + 187203584);      //      32,768 B  [bp][co]
  float* Spart = (float*)(ws + 187236352);   //  67,108,864 B  [kc][bp][j][i]

  hipMemsetAsync(svec, 0, 32768, stream);
  // x -> bf16 natural + column sums (pure stream), then bf16 -> bf16 transpose
  cast_x<<<1024, 256, 0, stream>>>(x, x_bf, svec);
  transpose_x<<<4096, 256, 0, stream>>>(x_bf, x_bfT);
  cast_f32_bf16<<<384, 256, 0, stream>>>(w_qkv, wqkv_bf, 786432 / 8);
  cast_f32_bf16<<<128, 256, 0, stream>>>(w_out, wout_bf, 262144 / 8);
  transpose_wv<<<16, 256, 0, stream>>>(w_qkv + 1024 * 512, wvT_bf);
  // S = X^T X per bp (symmetric: 10 upper-triangle tiles x 4 K-chunks), hi/lo split
  gemm5<0><<<dim3(40, 16), 256, 0, stream>>>(x_bfT, x_bfT, nullptr, Spart);
  s4red<<<4096, 256, 0, stream>>>(Spart, S_hi);
  // P = W_qk * (S_hi + S_lo)
  gemm5<1><<<512, 256, 0, stream>>>(wqkv_bf, S_hi, nullptr, P_bf);
  // Gram + norms + softmax + Weff
  softmax_weff2<<<128, 512, 0, stream>>>(P_bf, wqkv_bf, b_qkv, svec, temp, wout_bf, Weff);
  yb_kernel<<<16, 512, 0, stream>>>(Weff, b_qkv, b_out, yb);
  // M = Weff * Wv
  gemm5<2><<<256, 256, 0, stream>>>(Weff, wvT_bf, nullptr, M_bf);
  // y = X * M^T + yb
  gemm5<3><<<2048, 256, 0, stream>>>(M_bf, x_bf, yb, y);
}